// Round 5
// baseline (777.780 us; speedup 1.0000x reference)
//
#include <hip/hip_runtime.h>
#include <stdint.h>

// Cosine-similarity scores = normalize(pred) @ normalize(cand)^T
//   pred: 1024 x 4096 f32, cand: 16384 x 4096 f32, out: 1024 x 16384 f32
// Strategy: split-precision bf16x3 MFMA GEMM (a_hi*b_hi + a_lo*b_hi + a_hi*b_lo),
// error ~1e-6 (fp32-grade).
//   Plan A  (ws >= 285MB, M%256==0): norm+split preprocess into d_ws; 256x128
//     tile GEMM, 512 thr, LDS DOUBLE-BUFFERED (1 block/CU has no inter-block
//     overlap to hide the barrier drain — prefetch-into-other-buffer does).
//   Plan A' (ws >= 285MB, M%128==0): 128x128 tile GEMM (256 thr, 2 blk/CU).
//   Plan B  (ws >= 70KB): norms only in d_ws; GEMM reg-stages f32, converts
//     to hi/lo in-flight, applies norms at the epilogue.
//   Plan C  : zero-ws scalar fp32 fallback (correctness only).

#define KDIM 4096
#define NPROD 3   // 3 = fp32-grade; 1 = pure bf16 (3x less MFMA) — future A/B

typedef __attribute__((ext_vector_type(4))) float f32x4;
typedef __attribute__((ext_vector_type(8))) short bf16x8;
typedef __attribute__((ext_vector_type(4))) unsigned short u16x4;

typedef const __attribute__((address_space(1))) void as1_const_void;
typedef __attribute__((address_space(3))) void as3_void;

__device__ __forceinline__ unsigned short f32_bf16_rne(float f) {
  union { float f; uint32_t u; } c; c.f = f;
  uint32_t u = c.u;
  u += 0x7fffu + ((u >> 16) & 1u);   // round-to-nearest-even (finite inputs)
  return (unsigned short)(u >> 16);
}
__device__ __forceinline__ float bf16_f32(unsigned short h) {
  union { uint32_t u; float f; } c; c.u = ((uint32_t)h) << 16;
  return c.f;
}

// Row sum-of-squares reduction shared by the preprocess kernels.
// 256 threads, v[4] holds the row (16 f32/thread). Returns 1/max(norm,eps).
__device__ __forceinline__ float row_inv_norm(const f32x4 v[4], int t) {
  float s = 0.f;
#pragma unroll
  for (int j = 0; j < 4; ++j)
#pragma unroll
    for (int e = 0; e < 4; ++e) s += v[j][e] * v[j][e];
#pragma unroll
  for (int off = 32; off > 0; off >>= 1) s += __shfl_down(s, off, 64);
  __shared__ float red[4];
  if ((t & 63) == 0) red[t >> 6] = s;
  __syncthreads();
  const float tot = red[0] + red[1] + red[2] + red[3];
  return 1.0f / fmaxf(sqrtf(tot), 1e-8f);
}

// ---------------------------------------------------------------------------
// Plan A kernel 1: per-row norm + normalize + bf16 hi/lo split. 1 block/row.
// ---------------------------------------------------------------------------
__global__ __launch_bounds__(256) void normsplit_kernel(
    const float* __restrict__ pred, const float* __restrict__ cand,
    unsigned short* __restrict__ Ahi, unsigned short* __restrict__ Alo,
    unsigned short* __restrict__ Bhi, unsigned short* __restrict__ Blo,
    int n_pred) {
  const int row = blockIdx.x;
  const int t = threadIdx.x;
  const float* src;
  unsigned short *hi, *lo;
  int r;
  if (row < n_pred) { r = row;          src = pred; hi = Ahi; lo = Alo; }
  else              { r = row - n_pred; src = cand; hi = Bhi; lo = Blo; }

  const f32x4* p = (const f32x4*)(src + (size_t)r * KDIM);
  f32x4 v[4];
#pragma unroll
  for (int j = 0; j < 4; ++j) v[j] = p[t + 256 * j];
  const float inv = row_inv_norm(v, t);

  u16x4* hq = (u16x4*)(hi + (size_t)r * KDIM);
  u16x4* lq = (u16x4*)(lo + (size_t)r * KDIM);
#pragma unroll
  for (int j = 0; j < 4; ++j) {
    u16x4 h, l;
#pragma unroll
    for (int e = 0; e < 4; ++e) {
      float x = v[j][e] * inv;
      unsigned short hb = f32_bf16_rne(x);
      float resid = x - bf16_f32(hb);   // exact in f32
      h[e] = hb;
      l[e] = f32_bf16_rne(resid);
    }
    hq[t + 256 * j] = h;
    lq[t + 256 * j] = l;
  }
}

// ---------------------------------------------------------------------------
// Plan B kernel 1: per-row inv-norm only (70KB workspace). 1 block/row.
// ---------------------------------------------------------------------------
__global__ __launch_bounds__(256) void norms_kernel(
    const float* __restrict__ pred, const float* __restrict__ cand,
    float* __restrict__ inv_out, int n_pred) {
  const int row = blockIdx.x;
  const int t = threadIdx.x;
  const float* src = (row < n_pred) ? pred + (size_t)row * KDIM
                                    : cand + (size_t)(row - n_pred) * KDIM;
  const f32x4* p = (const f32x4*)src;
  f32x4 v[4];
#pragma unroll
  for (int j = 0; j < 4; ++j) v[j] = p[t + 256 * j];
  const float inv = row_inv_norm(v, t);
  if (t == 0) inv_out[row] = inv;
}

// ---------------------------------------------------------------------------
// Shared GEMM geometry. Tiles are [rows][32] bf16 LDS regions, 64B rows.
// Bank swizzle: 16B chunk c -> c ^ ((row>>1)&3), applied identically on the
// write side (pre-swizzled global source for global_load_lds / swizzled
// ds_write addr for plan B) and the ds_read side (both-sides involution,
// guide rule #21). Bank spread: rows 0..7 of a b128 frag read cover all 32
// banks exactly once; rows 8..15 repeat them — residual 2-way = free (m136).
// ---------------------------------------------------------------------------
__device__ __forceinline__ void frag_offsets_wm(int lane, int wm, int wn,
                                                int a_off[4], int b_off[4]) {
  const int cc = lane >> 4;
#pragma unroll
  for (int m = 0; m < 4; ++m) {
    const int rr = wm + m * 16 + (lane & 15);
    a_off[m] = rr * 64 + ((cc ^ ((rr >> 1) & 3)) << 4);
  }
#pragma unroll
  for (int n = 0; n < 4; ++n) {
    const int rr = wn + n * 16 + (lane & 15);
    b_off[n] = rr * 64 + ((cc ^ ((rr >> 1) & 3)) << 4);
  }
}

__device__ __forceinline__ int xcd_swizzle(int id, int nwg) {
  if ((nwg & 7) == 0) {
    const int cpx = nwg >> 3;
    id = (id & 7) * cpx + (id >> 3);   // bijective when nwg%8==0
  }
  return id;
}

// ---------------------------------------------------------------------------
// Plan A kernel 2: bf16x3 GEMM, BM=256 BN=128 BK=32, 512 threads (8 waves as
// 4M x 2N; each wave owns 64x64 = 4x4 frags of mfma_f32_16x16x32_bf16).
// LDS double-buffered (2 x 48KB): per K-step, stage(next buf) -> compute(cur)
// -> __syncthreads(). The barrier's built-in vmcnt(0) drain lands AFTER the
// ~1860-cycle MFMA phase, so the prefetched loads are already retired — the
// drain is free (guide T3 "minimum 2-phase" recipe; needed because 1 block/CU
// has no other block to compute through the drain). One barrier per K-step.
// Buffer layout (bytes, per 48KB buffer):
//   [0,16K) A-hi | [16K,32K) A-lo | [32K,40K) B-hi | [40K,48K) B-lo
// ---------------------------------------------------------------------------
#define BUF_SZ   49152
#define A_LO_OFF 16384
#define B_HI_OFF 32768
#define B_LO_OFF 40960

__global__ __launch_bounds__(512, 2) void gemm_x3_256_kernel(
    const unsigned short* __restrict__ Ahi, const unsigned short* __restrict__ Alo,
    const unsigned short* __restrict__ Bhi, const unsigned short* __restrict__ Blo,
    float* __restrict__ out, int M, int N) {
  __shared__ __align__(16) char lds[2 * BUF_SZ];   // 96 KB
  const int tid = threadIdx.x;
  const int lane = tid & 63;
  const int wave = tid >> 6;          // 0..7

  const int id = xcd_swizzle(blockIdx.x, gridDim.x);
  const int mblocks = M >> 8;         // M/256
  const int bm = id % mblocks;        // bm-fastest: blocks sharing a B-panel
  const int bn = id / mblocks;        // are dispatch-adjacent on one XCD
  const size_t row0 = (size_t)bm * 256;
  const size_t col0 = (size_t)bn * 128;

  // Staging geometry. A regions: 16KB = 2 shots of (512 thr x 16B); B: 1 shot.
  // LDS dest is wave-uniform base (+ lane*16 by HW); global source chunk is
  // pre-swizzled so the linear LDS image holds the swizzled layout.
  const unsigned short *gAh[2], *gAl[2], *gBh, *gBl;
  int loffA[2];
#pragma unroll
  for (int s = 0; s < 2; ++s) {
    const int p = s * 8192 + tid * 16;   // LDS byte this thread covers
    const int rr = p >> 6;               // tile row (64B rows: 32 bf16)
    const int cch = (p >> 4) & 3;        // 16B chunk within row
    const int e = (cch ^ ((rr >> 1) & 3)) * 8;
    gAh[s] = Ahi + (row0 + rr) * KDIM + e;
    gAl[s] = Alo + (row0 + rr) * KDIM + e;
    loffA[s] = s * 8192 + wave * 1024;   // wave-uniform LDS byte base
  }
  {
    const int p = tid * 16;
    const int rr = p >> 6;               // 0..127
    const int cch = (p >> 4) & 3;
    const int e = (cch ^ ((rr >> 1) & 3)) * 8;
    gBh = Bhi + (col0 + rr) * KDIM + e;
    gBl = Blo + (col0 + rr) * KDIM + e;
  }
  const int loffB = wave * 1024;

  const int wm = (wave >> 1) * 64;    // 0,64,128,192
  const int wn = (wave & 1) * 64;     // 0,64
  int a_off[4], b_off[4];
  frag_offsets_wm(lane, wm, wn, a_off, b_off);

  // Issue the 6 global_load_lds for one K-step into buffer base sb.
  auto stage = [&](int sb, int kt) {
#pragma unroll
    for (int s = 0; s < 2; ++s) {
      __builtin_amdgcn_global_load_lds((as1_const_void*)(gAh[s] + kt),
          (as3_void*)(lds + sb + loffA[s]), 16, 0, 0);
      __builtin_amdgcn_global_load_lds((as1_const_void*)(gAl[s] + kt),
          (as3_void*)(lds + sb + A_LO_OFF + loffA[s]), 16, 0, 0);
    }
    __builtin_amdgcn_global_load_lds((as1_const_void*)(gBh + kt),
        (as3_void*)(lds + sb + B_HI_OFF + loffB), 16, 0, 0);
    __builtin_amdgcn_global_load_lds((as1_const_void*)(gBl + kt),
        (as3_void*)(lds + sb + B_LO_OFF + loffB), 16, 0, 0);
  };

  f32x4 acc[4][4] = {};

  stage(0, 0);
  __syncthreads();   // prologue drain: buffer 0 ready
  int pb = 0;        // compute-buffer byte base, flips 0 <-> BUF_SZ

#pragma unroll 1
  for (int kt = 0; kt < KDIM; kt += 32) {
    if (kt + 32 < KDIM) stage(pb ^ BUF_SZ, kt + 32);  // prefetch next K-step

    bf16x8 fah[4], fal[4], fbh[4], fbl[4];
#pragma unroll
    for (int m = 0; m < 4; ++m) {
      fah[m] = *(const bf16x8*)(lds + pb + a_off[m]);
      fal[m] = *(const bf16x8*)(lds + pb + A_LO_OFF + a_off[m]);
    }
#pragma unroll
    for (int n = 0; n < 4; ++n) {
      fbh[n] = *(const bf16x8*)(lds + pb + B_HI_OFF + b_off[n]);
      fbl[n] = *(const bf16x8*)(lds + pb + B_LO_OFF + b_off[n]);
    }
#pragma unroll
    for (int m = 0; m < 4; ++m)
#pragma unroll
      for (int n = 0; n < 4; ++n) {
        acc[m][n] = __builtin_amdgcn_mfma_f32_16x16x32_bf16(fah[m], fbh[n], acc[m][n], 0, 0, 0);
        acc[m][n] = __builtin_amdgcn_mfma_f32_16x16x32_bf16(fal[m], fbh[n], acc[m][n], 0, 0, 0);
        acc[m][n] = __builtin_amdgcn_mfma_f32_16x16x32_bf16(fah[m], fbl[n], acc[m][n], 0, 0, 0);
      }

    __syncthreads();  // drains vmcnt: prefetched loads landed (had the whole
                      // MFMA phase to retire) + all waves done reading pb
    pb ^= BUF_SZ;
  }

  // Epilogue. C/D layout (m89-verified): col = lane&15, row = (lane>>4)*4 + reg.
  const int orow = (lane >> 4) * 4;
  const int ocol = lane & 15;
#pragma unroll
  for (int m = 0; m < 4; ++m)
#pragma unroll
    for (int n = 0; n < 4; ++n) {
      const size_t cbase = col0 + wn + n * 16 + ocol;
#pragma unroll
      for (int q = 0; q < 4; ++q) {
        const size_t rr = row0 + wm + m * 16 + orow + q;
        out[rr * (size_t)N + cbase] = acc[m][n][q];
      }
    }
}

// ---------------------------------------------------------------------------
// Plan A' kernel: 128x128 tile, 256 threads (4 waves 2x2), 2 blocks/CU —
// used when M%256 != 0. Single-buffered (inter-block overlap hides drain).
// ---------------------------------------------------------------------------
__global__ __launch_bounds__(256, 2) void gemm_x3_kernel(
    const unsigned short* __restrict__ Ahi, const unsigned short* __restrict__ Alo,
    const unsigned short* __restrict__ Bhi, const unsigned short* __restrict__ Blo,
    float* __restrict__ out, int M, int N) {
  __shared__ unsigned short sAhi[128 * 32], sAlo[128 * 32],
                            sBhi[128 * 32], sBlo[128 * 32];
  const int tid = threadIdx.x;
  const int lane = tid & 63;
  const int wave = tid >> 6;

  const int id = xcd_swizzle(blockIdx.x, gridDim.x);
  const int mblocks = M >> 7;
  const int bm = id % mblocks;
  const int bn = id / mblocks;
  const size_t row0 = (size_t)bm * 128;
  const size_t col0 = (size_t)bn * 128;

  const unsigned short *gAh[2], *gAl[2], *gBh[2], *gBl[2];
  int loff_[2];
#pragma unroll
  for (int it = 0; it < 2; ++it) {
    const int p = it * 4096 + wave * 1024 + lane * 16;
    const int rr = p >> 6;
    const int cch = (p >> 4) & 3;
    const int e = (cch ^ ((rr >> 1) & 3)) * 8;
    gAh[it] = Ahi + (row0 + rr) * KDIM + e;
    gAl[it] = Alo + (row0 + rr) * KDIM + e;
    gBh[it] = Bhi + (col0 + rr) * KDIM + e;
    gBl[it] = Blo + (col0 + rr) * KDIM + e;
    loff_[it] = it * 4096 + wave * 1024;
  }

  const int wm = (wave >> 1) * 64;
  const int wn = (wave & 1) * 64;
  int a_off[4], b_off[4];
  frag_offsets_wm(lane, wm, wn, a_off, b_off);

  f32x4 acc[4][4] = {};

#pragma unroll 1
  for (int kt = 0; kt < KDIM; kt += 32) {
#pragma unroll
    for (int it = 0; it < 2; ++it) {
      __builtin_amdgcn_global_load_lds((as1_const_void*)(gAh[it] + kt),
                                       (as3_void*)((char*)sAhi + loff_[it]), 16, 0, 0);
      __builtin_amdgcn_global_load_lds((as1_const_void*)(gBh[it] + kt),
                                       (as3_void*)((char*)sBhi + loff_[it]), 16, 0, 0);
#if NPROD >= 3
      __builtin_amdgcn_global_load_lds((as1_const_void*)(gAl[it] + kt),
                                       (as3_void*)((char*)sAlo + loff_[it]), 16, 0, 0);
      __builtin_amdgcn_global_load_lds((as1_const_void*)(gBl[it] + kt),
                                       (as3_void*)((char*)sBlo + loff_[it]), 16, 0, 0);
#endif
    }
    __syncthreads();

    bf16x8 fah[4], fbh[4];
#if NPROD >= 3
    bf16x8 fal[4], fbl[4];
#endif
#pragma unroll
    for (int m = 0; m < 4; ++m) {
      fah[m] = *(const bf16x8*)((const char*)sAhi + a_off[m]);
#if NPROD >= 3
      fal[m] = *(const bf16x8*)((const char*)sAlo + a_off[m]);
#endif
    }
#pragma unroll
    for (int n = 0; n < 4; ++n) {
      fbh[n] = *(const bf16x8*)((const char*)sBhi + b_off[n]);
#if NPROD >= 3
      fbl[n] = *(const bf16x8*)((const char*)sBlo + b_off[n]);
#endif
    }
#pragma unroll
    for (int m = 0; m < 4; ++m)
#pragma unroll
      for (int n = 0; n < 4; ++n) {
        acc[m][n] = __builtin_amdgcn_mfma_f32_16x16x32_bf16(fah[m], fbh[n], acc[m][n], 0, 0, 0);
#if NPROD >= 3
        acc[m][n] = __builtin_amdgcn_mfma_f32_16x16x32_bf16(fal[m], fbh[n], acc[m][n], 0, 0, 0);
        acc[m][n] = __builtin_amdgcn_mfma_f32_16x16x32_bf16(fah[m], fbl[n], acc[m][n], 0, 0, 0);
#endif
      }
    __syncthreads();
  }

  const int orow = (lane >> 4) * 4;
  const int ocol = lane & 15;
#pragma unroll
  for (int m = 0; m < 4; ++m)
#pragma unroll
    for (int n = 0; n < 4; ++n) {
      const size_t cbase = col0 + wn + n * 16 + ocol;
#pragma unroll
      for (int q = 0; q < 4; ++q) {
        const size_t rr = row0 + wm + m * 16 + orow + q;
        out[rr * (size_t)N + cbase] = acc[m][n][q];
      }
    }
}

// ---------------------------------------------------------------------------
// Plan B kernel 2: bf16x3 GEMM (128² tile), reg-staged f32->hi/lo conversion
// in-flight, norms applied at the epilogue. Needs only inv-norm workspace.
// ---------------------------------------------------------------------------
__global__ __launch_bounds__(256, 2) void gemm_fly_kernel(
    const float* __restrict__ A, const float* __restrict__ B,
    const float* __restrict__ invn, float* __restrict__ out, int M, int N) {
  __shared__ unsigned short sAhi[128 * 32], sAlo[128 * 32],
                            sBhi[128 * 32], sBlo[128 * 32];
  const int tid = threadIdx.x;
  const int lane = tid & 63;
  const int wave = tid >> 6;

  const int id = xcd_swizzle(blockIdx.x, gridDim.x);
  const int mblocks = M >> 7;
  const int bm = id % mblocks;
  const int bn = id / mblocks;
  const size_t row0 = (size_t)bm * 128;
  const size_t col0 = (size_t)bn * 128;

  // Staging: thread t owns row t>>1, cols (t&1)*16 .. +15 (16 f32 per matrix).
  const int srow = tid >> 1;
  const int scol = (tid & 1) * 16;
  int w_off[2];
#pragma unroll
  for (int g = 0; g < 2; ++g) {
    const int c = (scol >> 3) + g;              // absolute 8-elem chunk 0..3
    w_off[g] = srow * 64 + ((c ^ ((srow >> 1) & 3)) << 4);
  }

  const int wm = (wave >> 1) * 64;
  const int wn = (wave & 1) * 64;
  int a_off[4], b_off[4];
  frag_offsets_wm(lane, wm, wn, a_off, b_off);

  f32x4 acc[4][4] = {};

#pragma unroll 1
  for (int kt = 0; kt < KDIM; kt += 32) {
    const f32x4* pa = (const f32x4*)(A + (row0 + srow) * KDIM + kt + scol);
    const f32x4* pb = (const f32x4*)(B + (col0 + srow) * KDIM + kt + scol);
    f32x4 va[4], vb[4];
#pragma unroll
    for (int j = 0; j < 4; ++j) { va[j] = pa[j]; vb[j] = pb[j]; }

    bf16x8 ah[2], al[2], bh[2], bl[2];
#pragma unroll
    for (int g = 0; g < 2; ++g)
#pragma unroll
      for (int e = 0; e < 8; ++e) {
        float x = va[g * 2 + (e >> 2)][e & 3];
        unsigned short hb = f32_bf16_rne(x);
        ah[g][e] = (short)hb;
        al[g][e] = (short)f32_bf16_rne(x - bf16_f32(hb));
        x = vb[g * 2 + (e >> 2)][e & 3];
        hb = f32_bf16_rne(x);
        bh[g][e] = (short)hb;
        bl[g][e] = (short)f32_bf16_rne(x - bf16_f32(hb));
      }
    __syncthreads();  // protect LDS from previous iteration's readers
#pragma unroll
    for (int g = 0; g < 2; ++g) {
      *(bf16x8*)((char*)sAhi + w_off[g]) = ah[g];
      *(bf16x8*)((char*)sBhi + w_off[g]) = bh[g];
#if NPROD >= 3
      *(bf16x8*)((char*)sAlo + w_off[g]) = al[g];
      *(bf16x8*)((char*)sBlo + w_off[g]) = bl[g];
#endif
    }
    __syncthreads();

    bf16x8 fah[4], fbh[4];
#if NPROD >= 3
    bf16x8 fal[4], fbl[4];
#endif
#pragma unroll
    for (int m = 0; m < 4; ++m) {
      fah[m] = *(const bf16x8*)((const char*)sAhi + a_off[m]);
#if NPROD >= 3
      fal[m] = *(const bf16x8*)((const char*)sAlo + a_off[m]);
#endif
    }
#pragma unroll
    for (int n = 0; n < 4; ++n) {
      fbh[n] = *(const bf16x8*)((const char*)sBhi + b_off[n]);
#if NPROD >= 3
      fbl[n] = *(const bf16x8*)((const char*)sBlo + b_off[n]);
#endif
    }
#pragma unroll
    for (int m = 0; m < 4; ++m)
#pragma unroll
      for (int n = 0; n < 4; ++n) {
        acc[m][n] = __builtin_amdgcn_mfma_f32_16x16x32_bf16(fah[m], fbh[n], acc[m][n], 0, 0, 0);
#if NPROD >= 3
        acc[m][n] = __builtin_amdgcn_mfma_f32_16x16x32_bf16(fal[m], fbh[n], acc[m][n], 0, 0, 0);
        acc[m][n] = __builtin_amdgcn_mfma_f32_16x16x32_bf16(fah[m], fbl[n], acc[m][n], 0, 0, 0);
#endif
      }
  }

  const float* invP = invn;          // M entries
  const float* invC = invn + M;      // N entries
  const int orow = (lane >> 4) * 4;
  const int ocol = lane & 15;
#pragma unroll
  for (int m = 0; m < 4; ++m)
#pragma unroll
    for (int n = 0; n < 4; ++n) {
      const size_t cidx = col0 + wn + n * 16 + ocol;
      const float ib = invC[cidx];
#pragma unroll
      for (int q = 0; q < 4; ++q) {
        const size_t rr = row0 + wm + m * 16 + orow + q;
        out[rr * (size_t)N + cidx] = acc[m][n][q] * invP[rr] * ib;
      }
    }
}

// ---------------------------------------------------------------------------
// Plan C: zero-workspace scalar fp32 fallback (correctness only).
// ---------------------------------------------------------------------------
__global__ __launch_bounds__(256) void fallback_kernel(
    const float* __restrict__ A, const float* __restrict__ B,
    float* __restrict__ out, int M, int N) {
  __shared__ float sA[32][36], sB[32][36];
  __shared__ float invA[32], invB[32];
  __shared__ float part[64][4];
  const int t = threadIdx.x;
  const int bi = blockIdx.y;
  const int bj = blockIdx.x;
  const size_t r0a = (size_t)bi * 32, r0b = (size_t)bj * 32;

  {  // norms for the 64 rows this tile touches: 4 threads per row
    const int rr = t >> 2, seg = t & 3;
    const float* src = (rr < 32) ? (A + (r0a + rr) * KDIM)
                                 : (B + (r0b + rr - 32) * KDIM);
    const f32x4* p = (const f32x4*)src;
    float s = 0.f;
    for (int i = seg * 256; i < seg * 256 + 256; ++i) {
      f32x4 v = p[i];
      s += v[0] * v[0] + v[1] * v[1] + v[2] * v[2] + v[3] * v[3];
    }
    part[rr][seg] = s;
  }
  __syncthreads();
  if (t < 64) {
    const float s = part[t][0] + part[t][1] + part[t][2] + part[t][3];
    const float inv = 1.0f / fmaxf(sqrtf(s), 1e-8f);
    if (t < 32) invA[t] = inv; else invB[t - 32] = inv;
  }
  __syncthreads();

  float acc[4] = {0.f, 0.f, 0.f, 0.f};
  const int c = t & 31;
  const int rbase = t >> 5;
  for (int kt = 0; kt < KDIM; kt += 32) {
    const int rr = t >> 3, ccc = (t & 7) * 4;
    *(f32x4*)&sA[rr][ccc] = *(const f32x4*)(A + (r0a + rr) * KDIM + kt + ccc);
    *(f32x4*)&sB[rr][ccc] = *(const f32x4*)(B + (r0b + rr) * KDIM + kt + ccc);
    __syncthreads();
#pragma unroll
    for (int kk = 0; kk < 32; ++kk) {
      const float bv = sB[c][kk];
      acc[0] += sA[rbase][kk] * bv;
      acc[1] += sA[rbase + 8][kk] * bv;
      acc[2] += sA[rbase + 16][kk] * bv;
      acc[3] += sA[rbase + 24][kk] * bv;
    }
    __syncthreads();
  }
#pragma unroll
  for (int i = 0; i < 4; ++i) {
    const int rr = rbase + 8 * i;
    out[(r0a + rr) * (size_t)N + r0b + c] = acc[i] * invA[rr] * invB[c];
  }
}

// ---------------------------------------------------------------------------
extern "C" void kernel_launch(void* const* d_in, const int* in_sizes, int n_in,
                              void* d_out, int out_size, void* d_ws, size_t ws_size,
                              hipStream_t stream) {
  const float* pred = (const float*)d_in[0];
  const float* cand = (const float*)d_in[1];
  float* out = (float*)d_out;
  const int n_pred = in_sizes[0] / KDIM;
  const int n_cand = in_sizes[1] / KDIM;
  const int n_rows = n_pred + n_cand;

  const size_t need_big = (size_t)n_rows * KDIM * 2 * 2;     // hi+lo bf16
  const size_t need_small = (size_t)n_rows * sizeof(float);  // inv norms
  const bool shapes_ok = (n_pred % 128 == 0) && (n_cand % 128 == 0) &&
                         (n_pred * KDIM == in_sizes[0]) &&
                         (n_cand * KDIM == in_sizes[1]);

  if (shapes_ok && ws_size >= need_big) {
    unsigned short* Ahi = (unsigned short*)d_ws;
    unsigned short* Alo = Ahi + (size_t)n_pred * KDIM;
    unsigned short* Bhi = Alo + (size_t)n_pred * KDIM;
    unsigned short* Blo = Bhi + (size_t)n_cand * KDIM;
    normsplit_kernel<<<n_rows, 256, 0, stream>>>(pred, cand, Ahi, Alo, Bhi, Blo,
                                                 n_pred);
    if (n_pred % 256 == 0) {
      const int nwg = (n_pred / 256) * (n_cand / 128);
      gemm_x3_256_kernel<<<nwg, 512, 0, stream>>>(Ahi, Alo, Bhi, Blo, out,
                                                  n_pred, n_cand);
    } else {
      const int nwg = (n_pred / 128) * (n_cand / 128);
      gemm_x3_kernel<<<nwg, 256, 0, stream>>>(Ahi, Alo, Bhi, Blo, out, n_pred,
                                              n_cand);
    }
  } else if (shapes_ok && ws_size >= need_small) {
    float* invn = (float*)d_ws;
    const int nwg = (n_pred / 128) * (n_cand / 128);
    norms_kernel<<<n_rows, 256, 0, stream>>>(pred, cand, invn, n_pred);
    gemm_fly_kernel<<<nwg, 256, 0, stream>>>(pred, cand, invn, out, n_pred,
                                             n_cand);
  } else {
    dim3 grid(n_cand / 32, n_pred / 32);
    fallback_kernel<<<grid, 256, 0, stream>>>(pred, cand, out, n_pred, n_cand);
  }
}

// Round 7
// 623.565 us; speedup vs baseline: 1.2473x; 1.2473x over previous
//
#include <hip/hip_runtime.h>
#include <stdint.h>

// Cosine-similarity scores = normalize(pred) @ normalize(cand)^T
//   pred: 1024 x 4096 f32, cand: 16384 x 4096 f32, out: 1024 x 16384 f32
// Strategy: split-precision bf16x2 MFMA GEMM: C = ah*bh + al*bh  (A corrected
// to ~2^-18, B at bf16). True error ~7e-5. R5 data: bf16x3 ran MfmaUtil 45%,
// LDS/occupancy-bound (1 blk/CU @96KB LDS); x2 cuts LDS traffic + fits
// 2 blk/CU (2x40KB dbuf = 80KB). normsplit rebuilt wave-per-row (was 368us,
// 1.55 TB/s, block-barrier-bound).
//   Plan A  (ws ok, M%256==0): normsplit2 + 256x128 dbuf GEMM (512 thr).
//   Plan A' (ws ok, M%128==0): 128x128 tile GEMM (256 thr).
//   Plan B  (ws >= 70KB): norms only; GEMM converts f32->bf16 in-flight.
//   Plan C  : zero-ws scalar fp32 fallback (correctness only).

#define KDIM 4096
#define NPROD 2   // 2 = ah*bh+al*bh (~7e-5); 3 adds ah*bl (~1e-6); 1 = pure bf16

typedef __attribute__((ext_vector_type(4))) float f32x4;
typedef __attribute__((ext_vector_type(8))) short bf16x8;
typedef __attribute__((ext_vector_type(4))) unsigned short u16x4;

typedef const __attribute__((address_space(1))) void as1_const_void;
typedef __attribute__((address_space(3))) void as3_void;

__device__ __forceinline__ unsigned short f32_bf16_rne(float f) {
  union { float f; uint32_t u; } c; c.f = f;
  uint32_t u = c.u;
  u += 0x7fffu + ((u >> 16) & 1u);   // round-to-nearest-even (finite inputs)
  return (unsigned short)(u >> 16);
}
__device__ __forceinline__ float bf16_f32(unsigned short h) {
  union { uint32_t u; float f; } c; c.u = ((uint32_t)h) << 16;
  return c.f;
}

// ---------------------------------------------------------------------------
// Plan A kernel 1 (v2): wave-per-row norm + normalize + bf16 hi/lo split.
// 64 lanes x 64 f32 = one row per wave; butterfly __shfl_xor reduce (no LDS,
// no barriers); 4 rows per 256-thread block. A rows get hi+lo; B rows hi
// (+lo only if NPROD>=3).
// ---------------------------------------------------------------------------
__global__ __launch_bounds__(256) void normsplit2_kernel(
    const float* __restrict__ pred, const float* __restrict__ cand,
    unsigned short* __restrict__ Ahi, unsigned short* __restrict__ Alo,
    unsigned short* __restrict__ Bhi, unsigned short* __restrict__ Blo,
    int n_pred, int n_rows) {
  const int lane = threadIdx.x & 63;
  const int row = (blockIdx.x << 2) + (threadIdx.x >> 6);
  if (row >= n_rows) return;

  const float* src;
  unsigned short *hi, *lo;
  int r;
  bool has_lo;
  if (row < n_pred) {
    r = row; src = pred; hi = Ahi; lo = Alo; has_lo = true;
  } else {
    r = row - n_pred; src = cand; hi = Bhi; lo = Blo; has_lo = (NPROD >= 3);
  }

  const f32x4* p = (const f32x4*)(src + (size_t)r * KDIM);
  f32x4 v[16];
  float s = 0.f;
#pragma unroll
  for (int j = 0; j < 16; ++j) {
    v[j] = p[lane + 64 * j];          // wave covers contiguous 1KB per instr
#pragma unroll
    for (int e = 0; e < 4; ++e) s += v[j][e] * v[j][e];
  }
#pragma unroll
  for (int off = 32; off > 0; off >>= 1) s += __shfl_xor(s, off, 64);
  const float inv = 1.0f / fmaxf(sqrtf(s), 1e-8f);

  u16x4* hq = (u16x4*)(hi + (size_t)r * KDIM);
  if (has_lo) {
    u16x4* lq = (u16x4*)(lo + (size_t)r * KDIM);
#pragma unroll
    for (int j = 0; j < 16; ++j) {
      u16x4 h, l;
#pragma unroll
      for (int e = 0; e < 4; ++e) {
        const float x = v[j][e] * inv;
        const unsigned short hb = f32_bf16_rne(x);
        h[e] = hb;
        l[e] = f32_bf16_rne(x - bf16_f32(hb));   // resid exact in f32
      }
      hq[lane + 64 * j] = h;
      lq[lane + 64 * j] = l;
    }
  } else {
#pragma unroll
    for (int j = 0; j < 16; ++j) {
      u16x4 h;
#pragma unroll
      for (int e = 0; e < 4; ++e) h[e] = f32_bf16_rne(v[j][e] * inv);
      hq[lane + 64 * j] = h;
    }
  }
}

// ---------------------------------------------------------------------------
// Plan B kernel 1: per-row inv-norm only (70KB workspace). 1 wave/row.
// ---------------------------------------------------------------------------
__global__ __launch_bounds__(256) void norms_kernel(
    const float* __restrict__ pred, const float* __restrict__ cand,
    float* __restrict__ inv_out, int n_pred, int n_rows) {
  const int lane = threadIdx.x & 63;
  const int row = (blockIdx.x << 2) + (threadIdx.x >> 6);
  if (row >= n_rows) return;
  const float* src = (row < n_pred) ? pred + (size_t)row * KDIM
                                    : cand + (size_t)(row - n_pred) * KDIM;
  const f32x4* p = (const f32x4*)src;
  float s = 0.f;
#pragma unroll
  for (int j = 0; j < 16; ++j) {
    const f32x4 v = p[lane + 64 * j];
#pragma unroll
    for (int e = 0; e < 4; ++e) s += v[e] * v[e];
  }
#pragma unroll
  for (int off = 32; off > 0; off >>= 1) s += __shfl_xor(s, off, 64);
  if (lane == 0) inv_out[row] = 1.0f / fmaxf(sqrtf(s), 1e-8f);
}

// ---------------------------------------------------------------------------
// Shared GEMM geometry. Tiles are [rows][32] bf16 LDS regions, 64B rows.
// Bank swizzle: 16B chunk c -> c ^ ((row>>1)&3), applied identically on the
// write side (pre-swizzled global source for global_load_lds / swizzled
// ds_write addr for plan B) and the ds_read side (both-sides involution,
// guide rule #21). R5 PMC: SQ_LDS_BANK_CONFLICT == 0 — verified on HW.
// ---------------------------------------------------------------------------
__device__ __forceinline__ void frag_offsets_wm(int lane, int wm, int wn,
                                                int a_off[4], int b_off[4]) {
  const int cc = lane >> 4;
#pragma unroll
  for (int m = 0; m < 4; ++m) {
    const int rr = wm + m * 16 + (lane & 15);
    a_off[m] = rr * 64 + ((cc ^ ((rr >> 1) & 3)) << 4);
  }
#pragma unroll
  for (int n = 0; n < 4; ++n) {
    const int rr = wn + n * 16 + (lane & 15);
    b_off[n] = rr * 64 + ((cc ^ ((rr >> 1) & 3)) << 4);
  }
}

__device__ __forceinline__ int xcd_swizzle(int id, int nwg) {
  if ((nwg & 7) == 0) {
    const int cpx = nwg >> 3;
    id = (id & 7) * cpx + (id >> 3);   // bijective when nwg%8==0
  }
  return id;
}

// ---------------------------------------------------------------------------
// Plan A kernel 2: bf16x2 GEMM, BM=256 BN=128 BK=32, 512 threads (8 waves as
// 4M x 2N; each wave owns 64x64 = 4x4 frags of mfma_f32_16x16x32_bf16,
// 32 MFMA + 12 ds_read_b128 per K-step). LDS double-buffered 2 x 40KB = 80KB
// -> 2 blocks/CU (160KB exactly), 4 waves/SIMD for read/MFMA overlap that R5
// lacked at 1 blk/CU. launch_bounds(512,4) caps VGPR at 128 (R5 used 88).
// Buffer layout (bytes): [0,16K) A-hi | [16K,32K) A-lo | [32K,40K) B-hi
// ---------------------------------------------------------------------------
#define BUF_SZ   40960
#define A_LO_OFF 16384
#define B_HI_OFF 32768

__global__ __launch_bounds__(512, 4) void gemm_x2_256_kernel(
    const unsigned short* __restrict__ Ahi, const unsigned short* __restrict__ Alo,
    const unsigned short* __restrict__ Bhi,
    float* __restrict__ out, int M, int N) {
  __shared__ __align__(16) char lds[2 * BUF_SZ];   // 80 KB
  const int tid = threadIdx.x;
  const int lane = tid & 63;
  const int wave = tid >> 6;          // 0..7

  const int id = xcd_swizzle(blockIdx.x, gridDim.x);
  const int mblocks = M >> 8;         // M/256
  const int bm = id % mblocks;        // bm-fastest: blocks sharing a B-panel
  const int bn = id / mblocks;        // are dispatch-adjacent on one XCD
  const size_t row0 = (size_t)bm * 256;
  const size_t col0 = (size_t)bn * 128;

  // Staging geometry. A regions: 16KB = 2 shots of (512 thr x 16B); B: 1 shot.
  // LDS dest is wave-uniform base (+ lane*16 by HW); global source chunk is
  // pre-swizzled so the linear LDS image holds the swizzled layout.
  const unsigned short *gAh[2], *gAl[2], *gBh;
  int loffA[2];
#pragma unroll
  for (int s = 0; s < 2; ++s) {
    const int p = s * 8192 + tid * 16;   // LDS byte this thread covers
    const int rr = p >> 6;               // tile row (64B rows: 32 bf16)
    const int cch = (p >> 4) & 3;        // 16B chunk within row
    const int e = (cch ^ ((rr >> 1) & 3)) * 8;
    gAh[s] = Ahi + (row0 + rr) * KDIM + e;
    gAl[s] = Alo + (row0 + rr) * KDIM + e;
    loffA[s] = s * 8192 + wave * 1024;   // wave-uniform LDS byte base
  }
  {
    const int p = tid * 16;
    const int rr = p >> 6;               // 0..127
    const int cch = (p >> 4) & 3;
    const int e = (cch ^ ((rr >> 1) & 3)) * 8;
    gBh = Bhi + (col0 + rr) * KDIM + e;
  }
  const int loffB = wave * 1024;

  const int wm = (wave >> 1) * 64;    // 0,64,128,192
  const int wn = (wave & 1) * 64;     // 0,64
  int a_off[4], b_off[4];
  frag_offsets_wm(lane, wm, wn, a_off, b_off);

  // Issue the 5 global_load_lds for one K-step into buffer base sb.
  auto stage = [&](int sb, int kt) {
#pragma unroll
    for (int s = 0; s < 2; ++s) {
      __builtin_amdgcn_global_load_lds((as1_const_void*)(gAh[s] + kt),
          (as3_void*)(lds + sb + loffA[s]), 16, 0, 0);
      __builtin_amdgcn_global_load_lds((as1_const_void*)(gAl[s] + kt),
          (as3_void*)(lds + sb + A_LO_OFF + loffA[s]), 16, 0, 0);
    }
    __builtin_amdgcn_global_load_lds((as1_const_void*)(gBh + kt),
        (as3_void*)(lds + sb + B_HI_OFF + loffB), 16, 0, 0);
  };

  f32x4 acc[4][4] = {};

  stage(0, 0);
  __syncthreads();   // prologue drain: buffer 0 ready
  int pb = 0;        // compute-buffer byte base, flips 0 <-> BUF_SZ

#pragma unroll 1
  for (int kt = 0; kt < KDIM; kt += 32) {
    if (kt + 32 < KDIM) stage(pb ^ BUF_SZ, kt + 32);  // prefetch next K-step

    bf16x8 fah[4], fal[4], fbh[4];
#pragma unroll
    for (int m = 0; m < 4; ++m) {
      fah[m] = *(const bf16x8*)(lds + pb + a_off[m]);
      fal[m] = *(const bf16x8*)(lds + pb + A_LO_OFF + a_off[m]);
    }
#pragma unroll
    for (int n = 0; n < 4; ++n)
      fbh[n] = *(const bf16x8*)(lds + pb + B_HI_OFF + b_off[n]);

#pragma unroll
    for (int m = 0; m < 4; ++m)
#pragma unroll
      for (int n = 0; n < 4; ++n) {
        acc[m][n] = __builtin_amdgcn_mfma_f32_16x16x32_bf16(fah[m], fbh[n], acc[m][n], 0, 0, 0);
        acc[m][n] = __builtin_amdgcn_mfma_f32_16x16x32_bf16(fal[m], fbh[n], acc[m][n], 0, 0, 0);
      }

    __syncthreads();  // drains vmcnt: prefetched loads landed (had the whole
                      // MFMA phase to retire) + all waves done reading pb
    pb ^= BUF_SZ;
  }

  // Epilogue. C/D layout (m89-verified): col = lane&15, row = (lane>>4)*4 + reg.
  const int orow = (lane >> 4) * 4;
  const int ocol = lane & 15;
#pragma unroll
  for (int m = 0; m < 4; ++m)
#pragma unroll
    for (int n = 0; n < 4; ++n) {
      const size_t cbase = col0 + wn + n * 16 + ocol;
#pragma unroll
      for (int q = 0; q < 4; ++q) {
        const size_t rr = row0 + wm + m * 16 + orow + q;
        out[rr * (size_t)N + cbase] = acc[m][n][q];
      }
    }
}

// ---------------------------------------------------------------------------
// Plan A' kernel: 128x128 tile, 256 threads (4 waves 2x2) — used when
// M%256 != 0. Single-buffered (inter-block overlap hides drain).
// ---------------------------------------------------------------------------
__global__ __launch_bounds__(256, 2) void gemm_x2_128_kernel(
    const unsigned short* __restrict__ Ahi, const unsigned short* __restrict__ Alo,
    const unsigned short* __restrict__ Bhi,
    float* __restrict__ out, int M, int N) {
  __shared__ unsigned short sAhi[128 * 32], sBhi[128 * 32];
#if NPROD >= 2
  __shared__ unsigned short sAlo[128 * 32];
#endif
  const int tid = threadIdx.x;
  const int lane = tid & 63;
  const int wave = tid >> 6;

  const int id = xcd_swizzle(blockIdx.x, gridDim.x);
  const int mblocks = M >> 7;
  const int bm = id % mblocks;
  const int bn = id / mblocks;
  const size_t row0 = (size_t)bm * 128;
  const size_t col0 = (size_t)bn * 128;

  const unsigned short *gAh[2], *gAl[2], *gBh[2];
  int loff_[2];
#pragma unroll
  for (int it = 0; it < 2; ++it) {
    const int p = it * 4096 + wave * 1024 + lane * 16;
    const int rr = p >> 6;
    const int cch = (p >> 4) & 3;
    const int e = (cch ^ ((rr >> 1) & 3)) * 8;
    gAh[it] = Ahi + (row0 + rr) * KDIM + e;
    gAl[it] = Alo + (row0 + rr) * KDIM + e;
    gBh[it] = Bhi + (col0 + rr) * KDIM + e;
    loff_[it] = it * 4096 + wave * 1024;
  }

  const int wm = (wave >> 1) * 64;
  const int wn = (wave & 1) * 64;
  int a_off[4], b_off[4];
  frag_offsets_wm(lane, wm, wn, a_off, b_off);

  f32x4 acc[4][4] = {};

#pragma unroll 1
  for (int kt = 0; kt < KDIM; kt += 32) {
#pragma unroll
    for (int it = 0; it < 2; ++it) {
      __builtin_amdgcn_global_load_lds((as1_const_void*)(gAh[it] + kt),
                                       (as3_void*)((char*)sAhi + loff_[it]), 16, 0, 0);
      __builtin_amdgcn_global_load_lds((as1_const_void*)(gBh[it] + kt),
                                       (as3_void*)((char*)sBhi + loff_[it]), 16, 0, 0);
#if NPROD >= 2
      __builtin_amdgcn_global_load_lds((as1_const_void*)(gAl[it] + kt),
                                       (as3_void*)((char*)sAlo + loff_[it]), 16, 0, 0);
#endif
    }
    __syncthreads();

    bf16x8 fah[4], fbh[4];
#if NPROD >= 2
    bf16x8 fal[4];
#endif
#pragma unroll
    for (int m = 0; m < 4; ++m) {
      fah[m] = *(const bf16x8*)((const char*)sAhi + a_off[m]);
#if NPROD >= 2
      fal[m] = *(const bf16x8*)((const char*)sAlo + a_off[m]);
#endif
    }
#pragma unroll
    for (int n = 0; n < 4; ++n)
      fbh[n] = *(const bf16x8*)((const char*)sBhi + b_off[n]);
#pragma unroll
    for (int m = 0; m < 4; ++m)
#pragma unroll
      for (int n = 0; n < 4; ++n) {
        acc[m][n] = __builtin_amdgcn_mfma_f32_16x16x32_bf16(fah[m], fbh[n], acc[m][n], 0, 0, 0);
#if NPROD >= 2
        acc[m][n] = __builtin_amdgcn_mfma_f32_16x16x32_bf16(fal[m], fbh[n], acc[m][n], 0, 0, 0);
#endif
      }
    __syncthreads();
  }

  const int orow = (lane >> 4) * 4;
  const int ocol = lane & 15;
#pragma unroll
  for (int m = 0; m < 4; ++m)
#pragma unroll
    for (int n = 0; n < 4; ++n) {
      const size_t cbase = col0 + wn + n * 16 + ocol;
#pragma unroll
      for (int q = 0; q < 4; ++q) {
        const size_t rr = row0 + wm + m * 16 + orow + q;
        out[rr * (size_t)N + cbase] = acc[m][n][q];
      }
    }
}

// ---------------------------------------------------------------------------
// Plan B kernel 2: bf16x2 GEMM (128² tile), reg-staged f32->hi/lo conversion
// in-flight, norms applied at the epilogue. Needs only inv-norm workspace.
// ---------------------------------------------------------------------------
__global__ __launch_bounds__(256, 2) void gemm_fly_kernel(
    const float* __restrict__ A, const float* __restrict__ B,
    const float* __restrict__ invn, float* __restrict__ out, int M, int N) {
  __shared__ unsigned short sAhi[128 * 32], sBhi[128 * 32];
#if NPROD >= 2
  __shared__ unsigned short sAlo[128 * 32];
#endif
  const int tid = threadIdx.x;
  const int lane = tid & 63;
  const int wave = tid >> 6;

  const int id = xcd_swizzle(blockIdx.x, gridDim.x);
  const int mblocks = M >> 7;
  const int bm = id % mblocks;
  const int bn = id / mblocks;
  const size_t row0 = (size_t)bm * 128;
  const size_t col0 = (size_t)bn * 128;

  // Staging: thread t owns row t>>1, cols (t&1)*16 .. +15 (16 f32 per matrix).
  const int srow = tid >> 1;
  const int scol = (tid & 1) * 16;
  int w_off[2];
#pragma unroll
  for (int g = 0; g < 2; ++g) {
    const int c = (scol >> 3) + g;              // absolute 8-elem chunk 0..3
    w_off[g] = srow * 64 + ((c ^ ((srow >> 1) & 3)) << 4);
  }

  const int wm = (wave >> 1) * 64;
  const int wn = (wave & 1) * 64;
  int a_off[4], b_off[4];
  frag_offsets_wm(lane, wm, wn, a_off, b_off);

  f32x4 acc[4][4] = {};

#pragma unroll 1
  for (int kt = 0; kt < KDIM; kt += 32) {
    const f32x4* pa = (const f32x4*)(A + (row0 + srow) * KDIM + kt + scol);
    const f32x4* pb = (const f32x4*)(B + (col0 + srow) * KDIM + kt + scol);
    f32x4 va[4], vb[4];
#pragma unroll
    for (int j = 0; j < 4; ++j) { va[j] = pa[j]; vb[j] = pb[j]; }

    bf16x8 ah[2], al[2], bh[2];
#pragma unroll
    for (int g = 0; g < 2; ++g)
#pragma unroll
      for (int e = 0; e < 8; ++e) {
        float x = va[g * 2 + (e >> 2)][e & 3];
        unsigned short hb = f32_bf16_rne(x);
        ah[g][e] = (short)hb;
        al[g][e] = (short)f32_bf16_rne(x - bf16_f32(hb));
        x = vb[g * 2 + (e >> 2)][e & 3];
        bh[g][e] = (short)f32_bf16_rne(x);
      }
    __syncthreads();  // protect LDS from previous iteration's readers
#pragma unroll
    for (int g = 0; g < 2; ++g) {
      *(bf16x8*)((char*)sAhi + w_off[g]) = ah[g];
      *(bf16x8*)((char*)sBhi + w_off[g]) = bh[g];
#if NPROD >= 2
      *(bf16x8*)((char*)sAlo + w_off[g]) = al[g];
#endif
    }
    __syncthreads();

    bf16x8 fah[4], fbh[4];
#if NPROD >= 2
    bf16x8 fal[4];
#endif
#pragma unroll
    for (int m = 0; m < 4; ++m) {
      fah[m] = *(const bf16x8*)((const char*)sAhi + a_off[m]);
#if NPROD >= 2
      fal[m] = *(const bf16x8*)((const char*)sAlo + a_off[m]);
#endif
    }
#pragma unroll
    for (int n = 0; n < 4; ++n)
      fbh[n] = *(const bf16x8*)((const char*)sBhi + b_off[n]);
#pragma unroll
    for (int m = 0; m < 4; ++m)
#pragma unroll
      for (int n = 0; n < 4; ++n) {
        acc[m][n] = __builtin_amdgcn_mfma_f32_16x16x32_bf16(fah[m], fbh[n], acc[m][n], 0, 0, 0);
#if NPROD >= 2
        acc[m][n] = __builtin_amdgcn_mfma_f32_16x16x32_bf16(fal[m], fbh[n], acc[m][n], 0, 0, 0);
#endif
      }
  }

  const float* invP = invn;          // M entries
  const float* invC = invn + M;      // N entries
  const int orow = (lane >> 4) * 4;
  const int ocol = lane & 15;
#pragma unroll
  for (int m = 0; m < 4; ++m)
#pragma unroll
    for (int n = 0; n < 4; ++n) {
      const size_t cidx = col0 + wn + n * 16 + ocol;
      const float ib = invC[cidx];
#pragma unroll
      for (int q = 0; q < 4; ++q) {
        const size_t rr = row0 + wm + m * 16 + orow + q;
        out[rr * (size_t)N + cidx] = acc[m][n][q] * invP[rr] * ib;
      }
    }
}

// ---------------------------------------------------------------------------
// Plan C: zero-workspace scalar fp32 fallback (correctness only).
// ---------------------------------------------------------------------------
__global__ __launch_bounds__(256) void fallback_kernel(
    const float* __restrict__ A, const float* __restrict__ B,
    float* __restrict__ out, int M, int N) {
  __shared__ float sA[32][36], sB[32][36];
  __shared__ float invA[32], invB[32];
  __shared__ float part[64][4];
  const int t = threadIdx.x;
  const int bi = blockIdx.y;
  const int bj = blockIdx.x;
  const size_t r0a = (size_t)bi * 32, r0b = (size_t)bj * 32;

  {  // norms for the 64 rows this tile touches: 4 threads per row
    const int rr = t >> 2, seg = t & 3;
    const float* src = (rr < 32) ? (A + (r0a + rr) * KDIM)
                                 : (B + (r0b + rr - 32) * KDIM);
    const f32x4* p = (const f32x4*)src;
    float s = 0.f;
    for (int i = seg * 256; i < seg * 256 + 256; ++i) {
      f32x4 v = p[i];
      s += v[0] * v[0] + v[1] * v[1] + v[2] * v[2] + v[3] * v[3];
    }
    part[rr][seg] = s;
  }
  __syncthreads();
  if (t < 64) {
    const float s = part[t][0] + part[t][1] + part[t][2] + part[t][3];
    const float inv = 1.0f / fmaxf(sqrtf(s), 1e-8f);
    if (t < 32) invA[t] = inv; else invB[t - 32] = inv;
  }
  __syncthreads();

  float acc[4] = {0.f, 0.f, 0.f, 0.f};
  const int c = t & 31;
  const int rbase = t >> 5;
  for (int kt = 0; kt < KDIM; kt += 32) {
    const int rr = t >> 3, ccc = (t & 7) * 4;
    *(f32x4*)&sA[rr][ccc] = *(const f32x4*)(A + (r0a + rr) * KDIM + kt + ccc);
    *(f32x4*)&sB[rr][ccc] = *(const f32x4*)(B + (r0b + rr) * KDIM + kt + ccc);
    __syncthreads();
#pragma unroll
    for (int kk = 0; kk < 32; ++kk) {
      const float bv = sB[c][kk];
      acc[0] += sA[rbase][kk] * bv;
      acc[1] += sA[rbase + 8][kk] * bv;
      acc[2] += sA[rbase + 16][kk] * bv;
      acc[3] += sA[rbase + 24][kk] * bv;
    }
    __syncthreads();
  }
#pragma unroll
  for (int i = 0; i < 4; ++i) {
    const int rr = rbase + 8 * i;
    out[(r0a + rr) * (size_t)N + r0b + c] = acc[i] * invA[rr] * invB[c];
  }
}

// ---------------------------------------------------------------------------
extern "C" void kernel_launch(void* const* d_in, const int* in_sizes, int n_in,
                              void* d_out, int out_size, void* d_ws, size_t ws_size,
                              hipStream_t stream) {
  const float* pred = (const float*)d_in[0];
  const float* cand = (const float*)d_in[1];
  float* out = (float*)d_out;
  const int n_pred = in_sizes[0] / KDIM;
  const int n_cand = in_sizes[1] / KDIM;
  const int n_rows = n_pred + n_cand;

  // Workspace: Ahi | Alo | Bhi | (Blo if NPROD>=3), bf16 row-major.
  const size_t elems_big =
      (size_t)(2 * n_pred + (NPROD >= 3 ? 2 : 1) * n_cand) * KDIM;
  const size_t need_big = elems_big * 2;
  const size_t need_small = (size_t)n_rows * sizeof(float);
  const bool shapes_ok = (n_pred % 128 == 0) && (n_cand % 128 == 0) &&
                         (n_pred * KDIM == in_sizes[0]) &&
                         (n_cand * KDIM == in_sizes[1]);

  if (shapes_ok && ws_size >= need_big) {
    unsigned short* Ahi = (unsigned short*)d_ws;
    unsigned short* Alo = Ahi + (size_t)n_pred * KDIM;
    unsigned short* Bhi = Alo + (size_t)n_pred * KDIM;
    unsigned short* Blo = Bhi + (size_t)n_cand * KDIM;  // used iff NPROD>=3
    normsplit2_kernel<<<(n_rows + 3) / 4, 256, 0, stream>>>(
        pred, cand, Ahi, Alo, Bhi, Blo, n_pred, n_rows);
    if (n_pred % 256 == 0) {
      const int nwg = (n_pred / 256) * (n_cand / 128);
      gemm_x2_256_kernel<<<nwg, 512, 0, stream>>>(Ahi, Alo, Bhi, out,
                                                  n_pred, n_cand);
    } else {
      const int nwg = (n_pred / 128) * (n_cand / 128);
      gemm_x2_128_kernel<<<nwg, 256, 0, stream>>>(Ahi, Alo, Bhi, out,
                                                  n_pred, n_cand);
    }
  } else if (shapes_ok && ws_size >= need_small) {
    float* invn = (float*)d_ws;
    const int nwg = (n_pred / 128) * (n_cand / 128);
    norms_kernel<<<(n_rows + 3) / 4, 256, 0, stream>>>(pred, cand, invn,
                                                       n_pred, n_rows);
    gemm_fly_kernel<<<nwg, 256, 0, stream>>>(pred, cand, invn, out, n_pred,
                                             n_cand);
  } else {
    dim3 grid(n_cand / 32, n_pred / 32);
    fallback_kernel<<<grid, 256, 0, stream>>>(pred, cand, out, n_pred, n_cand);
  }
}